// Round 2
// baseline (855.394 us; speedup 1.0000x reference)
//
#include <hip/hip_runtime.h>

#define HDIM 128
#define NGRAPH 64
#define NCLASS 7

// ---------------- setup: degrees (by dst and by src), dinv ----------------

__global__ void k_count(const int* __restrict__ row, const int* __restrict__ col, int E,
                        int* __restrict__ degAll, int n) {
  int e = blockIdx.x * blockDim.x + threadIdx.x;
  if (e < E) {
    atomicAdd(&degAll[col[e]], 1);      // in-degree (aggregation dst)
    atomicAdd(&degAll[n + row[e]], 1);  // out-degree (src)
  }
}

__global__ void k_dinv(const int* __restrict__ degAll, float* __restrict__ dinv, int n) {
  int i = blockIdx.x * blockDim.x + threadIdx.x;
  if (i < n) dinv[i] = rsqrtf((float)(degAll[i] + 1));  // +1 self-loop
}

// exclusive scan of degAll[0..2n) -> offAll, writing with +1 index shift for i>=n
// offAll layout: [0..n] = col-CSR offsets, [n+1..2n+1] = row-CSR offsets
__global__ void k_scan1(const int* __restrict__ in, int n2, int n, int* __restrict__ outAll,
                        int* __restrict__ tileSums) {
  __shared__ int sh[256];
  int t = threadIdx.x;
  int base = blockIdx.x * 1024 + t * 4;
  int v[4], sum = 0;
#pragma unroll
  for (int j = 0; j < 4; j++) {
    int idx = base + j;
    int x = (idx < n2) ? in[idx] : 0;
    v[j] = sum; sum += x;
  }
  sh[t] = sum; __syncthreads();
  for (int o = 1; o < 256; o <<= 1) {
    int val = (t >= o) ? sh[t - o] : 0;
    __syncthreads();
    sh[t] += val;
    __syncthreads();
  }
  int excl = (t == 0) ? 0 : sh[t - 1];
  if (t == 255) tileSums[blockIdx.x] = sh[255];
#pragma unroll
  for (int j = 0; j < 4; j++) {
    int idx = base + j;
    if (idx < n2) outAll[idx + (idx >= n ? 1 : 0)] = excl + v[j];
  }
}

__global__ void k_scan2(int* __restrict__ tileSums, int numTiles) {
  __shared__ int sh[256];
  int t = threadIdx.x;
  sh[t] = (t < numTiles) ? tileSums[t] : 0;
  __syncthreads();
  for (int o = 1; o < 256; o <<= 1) {
    int val = (t >= o) ? sh[t - o] : 0;
    __syncthreads();
    sh[t] += val;
    __syncthreads();
  }
  if (t < numTiles) tileSums[t] = (t == 0) ? 0 : sh[t - 1];
}

__global__ void k_scan3(int* __restrict__ offAll, const int* __restrict__ tileSums,
                        int n2, int n, int E) {
  int i = blockIdx.x * blockDim.x + threadIdx.x;
  if (i < n2) {
    int pos = i + (i >= n ? 1 : 0);
    int adj = tileSums[i >> 10] - (i >= n ? E : 0);
    offAll[pos] += adj;
  }
  if (i == 0) { offAll[n] = E; offAll[n2 + 1] = E; }
}

// build both CSRs in one pass
__global__ void k_scatter(const int* __restrict__ row, const int* __restrict__ col, int E,
                          const int* __restrict__ offAll, int* __restrict__ curAll,
                          const float* __restrict__ dinv, const int* __restrict__ batch,
                          int* __restrict__ srcIdx, float* __restrict__ enorm,
                          int* __restrict__ gS, float* __restrict__ wS, int n) {
  int e = blockIdx.x * blockDim.x + threadIdx.x;
  if (e >= E) return;
  int r = row[e], c = col[e];
  float w = dinv[r] * dinv[c];
  int pC = offAll[c] + atomicAdd(&curAll[c], 1);
  srcIdx[pC] = r;
  enorm[pC] = w;
  int pR = offAll[n + 1 + r] + atomicAdd(&curAll[n + r], 1);
  gS[pR] = batch[c];
  wS[pR] = w;
}

// ---------------- layer 1: s = A_norm . x (scalar aggregation) ----------------

__global__ void k_layer1(const float* __restrict__ x, const int* __restrict__ off,
                         const int* __restrict__ srcIdx, const float* __restrict__ enorm,
                         const float* __restrict__ dinv, float* __restrict__ s, int n) {
  int i = blockIdx.x * blockDim.x + threadIdx.x;
  if (i >= n) return;
  float di = dinv[i];
  float acc = di * di * x[i];
  int e0 = off[i], e1 = off[i + 1];
  for (int e = e0; e < e1; e++) acc = fmaf(enorm[e], x[srcIdx[e]], acc);
  s[i] = acc;
}

// ---------------- fused: h1 = relu(s*W1+b1) recomputed per edge + agg2 ----------------
// z[i][j] = nself*relu(s[i]W1[j]+b1[j]) + sum_e w_e * relu(s[src]W1[j]+b1[j])

__global__ void __launch_bounds__(256) k_l2in(const float* __restrict__ s,
                                              const int* __restrict__ off,
                                              const int* __restrict__ srcIdx,
                                              const float* __restrict__ enorm,
                                              const float* __restrict__ dinv,
                                              const float* __restrict__ W1,
                                              const float* __restrict__ b1,
                                              float2* __restrict__ z, int n) {
  int node = blockIdx.x * 4 + (threadIdx.x >> 6);
  if (node >= n) return;
  int l = threadIdx.x & 63;
  float2 w1 = ((const float2*)W1)[l];
  float2 bv = ((const float2*)b1)[l];
  float di = dinv[node];
  float nself = di * di;
  float sv = s[node];
  float2 acc;
  acc.x = nself * fmaxf(fmaf(sv, w1.x, bv.x), 0.f);
  acc.y = nself * fmaxf(fmaf(sv, w1.y, bv.y), 0.f);
  int e0 = off[node], e1 = off[node + 1];
  for (int e = e0; e < e1; e++) {
    float ss = s[srcIdx[e]];
    float w = enorm[e];
    acc.x = fmaf(w, fmaxf(fmaf(ss, w1.x, bv.x), 0.f), acc.x);
    acc.y = fmaf(w, fmaxf(fmaf(ss, w1.y, bv.y), 0.f), acc.y);
  }
  z[(size_t)node * 64 + l] = acc;
}

// ---------------- GEMM: (n x 128) @ (128 x 128) + bias + relu ----------------
// 64r x 64c tile, 256 threads, 4x4 register tile, k-vectorized b128 reads.
// As[64][128] row-major, XOR-quad-swizzled: float4 slot = r*32 + ((k>>2) ^ ((r>>2)&7))
// Wt[64][128] col-major (Wt[c][k]), same swizzle on k-quads vs (c>>2)&7.

template <bool RELU>
__global__ void __launch_bounds__(256, 2)
k_gemm(const float* __restrict__ A, const float* __restrict__ W,
       const float* __restrict__ bias, float* __restrict__ out, int n) {
  __shared__ float4 As4[64 * 32];
  __shared__ float4 Wt4[64 * 32];
  float* Wt = (float*)Wt4;
  const int t = threadIdx.x;
  const int colBase = blockIdx.y << 6;

  // stage Wt (transposed + swizzled) once per block
  for (int l = t; l < 2048; l += 256) {
    int k = l >> 4, c4 = (l & 15) << 2;
    float4 wv = *(const float4*)&W[k * 128 + colBase + c4];
    int kq = k >> 2, kl = k & 3;
    int u = (c4 >> 2) & 7;
    int slot = ((kq ^ u) << 2) | kl;
    Wt[(c4 + 0) * 128 + slot] = wv.x;
    Wt[(c4 + 1) * 128 + slot] = wv.y;
    Wt[(c4 + 2) * 128 + slot] = wv.z;
    Wt[(c4 + 3) * 128 + slot] = wv.w;
  }

  const int cg = (t & 15) << 2;   // 4 cols
  const int rg = (t >> 4) << 2;   // 4 rows
  const int ra = (rg >> 2) & 7;
  const int ca = (cg >> 2) & 7;
  const float4 bv = *(const float4*)&bias[colBase + cg];
  const int numTiles = (n + 63) >> 6;

  for (int tile = blockIdx.x; tile < numTiles; tile += gridDim.x) {
    const int rowBase = tile << 6;
    __syncthreads();  // protects As reuse (and covers Wt staging on first iter)
    for (int l = t; l < 2048; l += 256) {
      int r = l >> 5, kq = l & 31;
      int row = rowBase + r;
      float4 a = (row < n) ? *(const float4*)&A[(size_t)row * 128 + (kq << 2)]
                           : make_float4(0.f, 0.f, 0.f, 0.f);
      As4[r * 32 + (kq ^ ((r >> 2) & 7))] = a;
    }
    __syncthreads();

    float acc[4][4] = {};
    const float4* a0p = &As4[(rg + 0) * 32];
    const float4* a1p = &As4[(rg + 1) * 32];
    const float4* a2p = &As4[(rg + 2) * 32];
    const float4* a3p = &As4[(rg + 3) * 32];
    const float4* w0p = &Wt4[(cg + 0) * 32];
    const float4* w1p = &Wt4[(cg + 1) * 32];
    const float4* w2p = &Wt4[(cg + 2) * 32];
    const float4* w3p = &Wt4[(cg + 3) * 32];
#pragma unroll 8
    for (int kq = 0; kq < 32; kq++) {
      int ia = kq ^ ra, iw = kq ^ ca;
      float4 a[4] = { a0p[ia], a1p[ia], a2p[ia], a3p[ia] };
      float4 w[4] = { w0p[iw], w1p[iw], w2p[iw], w3p[iw] };
#pragma unroll
      for (int i = 0; i < 4; i++)
#pragma unroll
        for (int j = 0; j < 4; j++) {
          float v = acc[i][j];
          v = fmaf(a[i].x, w[j].x, v);
          v = fmaf(a[i].y, w[j].y, v);
          v = fmaf(a[i].z, w[j].z, v);
          v = fmaf(a[i].w, w[j].w, v);
          acc[i][j] = v;
        }
    }

#pragma unroll
    for (int i = 0; i < 4; i++) {
      int row = rowBase + rg + i;
      if (row < n) {
        float4 o4;
        o4.x = acc[i][0] + bv.x;
        o4.y = acc[i][1] + bv.y;
        o4.z = acc[i][2] + bv.z;
        o4.w = acc[i][3] + bv.w;
        if (RELU) {
          o4.x = fmaxf(o4.x, 0.f); o4.y = fmaxf(o4.y, 0.f);
          o4.z = fmaxf(o4.z, 0.f); o4.w = fmaxf(o4.w, 0.f);
        }
        *(float4*)&out[(size_t)row * 128 + colBase + cg] = o4;
      }
    }
  }
}

// ---------------- fused layer-3 aggregation + pooling ----------------
// pooled[g][:] = sum_src h2[src][:] * (self coef + sum of out-edge coefs into g)
// Streams h2 sequentially; accumulates in per-block LDS; flushes with atomics.

__global__ void __launch_bounds__(256) k_agg3pool(const float2* __restrict__ h2,
                                                  const int* __restrict__ offR,
                                                  const int* __restrict__ gS,
                                                  const float* __restrict__ wS,
                                                  const float* __restrict__ dinv,
                                                  const int* __restrict__ batch,
                                                  float* __restrict__ pooled, int n) {
  __shared__ float lp[NGRAPH * HDIM];
  for (int i = threadIdx.x; i < NGRAPH * HDIM; i += 256) lp[i] = 0.f;
  __syncthreads();
  int lane = threadIdx.x & 63;
  int wv = threadIdx.x >> 6;
  int per = (n + gridDim.x - 1) / gridDim.x;
  int s0 = blockIdx.x * per;
  int s1 = min(s0 + per, n);
  for (int src = s0 + wv; src < s1; src += 4) {
    float2 h = h2[(size_t)src * 64 + lane];
    float di = dinv[src];
    int g = batch[src];
    float w = di * di;  // self-loop coef
    atomicAdd(&lp[g * HDIM + lane * 2], w * h.x);
    atomicAdd(&lp[g * HDIM + lane * 2 + 1], w * h.y);
    int e0 = offR[src], e1 = offR[src + 1];
    for (int e = e0; e < e1; e++) {
      int ge = gS[e];
      float we = wS[e];
      atomicAdd(&lp[ge * HDIM + lane * 2], we * h.x);
      atomicAdd(&lp[ge * HDIM + lane * 2 + 1], we * h.y);
    }
  }
  __syncthreads();
  for (int i = threadIdx.x; i < NGRAPH * HDIM; i += 256) {
    float v = lp[i];
    if (v != 0.f) atomicAdd(&pooled[i], v);
  }
}

// graph sizes via binary search on sorted batch (one wave)
__global__ void k_gcount(const int* __restrict__ batch, float* __restrict__ gcount, int n) {
  int g = threadIdx.x;
  if (g >= NGRAPH) return;
  int lo = 0, hi = n;
  while (lo < hi) { int m = (lo + hi) >> 1; if (batch[m] < g) lo = m + 1; else hi = m; }
  int a = lo;
  lo = 0; hi = n;
  while (lo < hi) { int m = (lo + hi) >> 1; if (batch[m] < g + 1) lo = m + 1; else hi = m; }
  gcount[g] = (float)(lo - a);
}

// t1[g][j] = (pooledSum[g] . W3[:,j]) / cnt[g] + b3[j]
__global__ void k_mid(const float* __restrict__ pooled, const float* __restrict__ gcount,
                      const float* __restrict__ W3, const float* __restrict__ b3,
                      float* __restrict__ t1) {
  int g = blockIdx.x, j = threadIdx.x;
  float inv = 1.f / fmaxf(gcount[g], 1.f);
  float acc = 0.f;
  for (int k = 0; k < HDIM; k++) acc = fmaf(pooled[g * HDIM + k], W3[k * HDIM + j], acc);
  t1[g * HDIM + j] = acc * inv + b3[j];
}

__global__ void k_out(const float* __restrict__ t1, const float* __restrict__ Wl,
                      const float* __restrict__ bl, float* __restrict__ out) {
  int t = threadIdx.x;
  int g = t >> 3, c = t & 7;
  if (g >= NGRAPH || c >= NCLASS) return;
  float acc = 0.f;
  for (int k = 0; k < HDIM; k++) acc = fmaf(t1[g * HDIM + k], Wl[k * NCLASS + c], acc);
  out[g * NCLASS + c] = acc + bl[c];
}

// ---------------- host ----------------

extern "C" void kernel_launch(void* const* d_in, const int* in_sizes, int n_in,
                              void* d_out, int out_size, void* d_ws, size_t ws_size,
                              hipStream_t stream) {
  const float* x   = (const float*)d_in[0];
  const int*   ei  = (const int*)d_in[1];
  const int*   bat = (const int*)d_in[2];
  const float* W1  = (const float*)d_in[3];
  const float* b1  = (const float*)d_in[4];
  const float* W2  = (const float*)d_in[5];
  const float* b2  = (const float*)d_in[6];
  const float* W3  = (const float*)d_in[7];
  const float* b3  = (const float*)d_in[8];
  const float* Wl  = (const float*)d_in[9];
  const float* bl  = (const float*)d_in[10];
  float* out = (float*)d_out;

  const int n = in_sizes[0];       // N (F_IN == 1)
  const int E = in_sizes[1] / 2;
  const int* rowv = ei;            // edge_index[0] : message source
  const int* colv = ei + E;        // edge_index[1] : aggregation destination

  char* w = (char*)d_ws;
  size_t o = 0;
  auto alloc = [&](size_t bytes) {
    size_t r = (o + 255) & ~(size_t)255;
    o = r + bytes;
    return r;
  };
  // zero-init region (contiguous): degAll(2n), curAll(2n), pooled
  size_t o_deg  = alloc((size_t)2 * n * 4);
  size_t o_cur  = alloc((size_t)2 * n * 4);
  size_t o_pool = alloc((size_t)NGRAPH * HDIM * 4);
  size_t zero_end = o;
  size_t o_off  = alloc(((size_t)2 * n + 2) * 4);
  size_t o_ts   = alloc(256 * 4);
  size_t o_dinv = alloc((size_t)n * 4);
  size_t o_s    = alloc((size_t)n * 4);
  size_t o_gcnt = alloc((size_t)NGRAPH * 4);
  size_t o_t1   = alloc((size_t)NGRAPH * HDIM * 4);
  size_t o_src  = alloc((size_t)E * 4);
  size_t o_nrm  = alloc((size_t)E * 4);
  size_t o_gS   = alloc((size_t)E * 4);
  size_t o_wS   = alloc((size_t)E * 4);
  size_t o_bufA = alloc((size_t)n * HDIM * 4);
  size_t o_bufB = alloc((size_t)n * HDIM * 4);
  (void)ws_size; (void)n_in; (void)out_size;

  int*   degAll = (int*)(w + o_deg);
  int*   curAll = (int*)(w + o_cur);
  float* pooled = (float*)(w + o_pool);
  int*   offAll = (int*)(w + o_off);
  int*   ts     = (int*)(w + o_ts);
  float* dinv   = (float*)(w + o_dinv);
  float* s      = (float*)(w + o_s);
  float* gcount = (float*)(w + o_gcnt);
  float* t1     = (float*)(w + o_t1);
  int*   srcIdx = (int*)(w + o_src);
  float* enorm  = (float*)(w + o_nrm);
  int*   gS     = (int*)(w + o_gS);
  float* wS     = (float*)(w + o_wS);
  float* bufA   = (float*)(w + o_bufA);  // h2 (gemm out)
  float* bufB   = (float*)(w + o_bufB);  // gemm in (fused agg2 out)

  hipMemsetAsync(w + o_deg, 0, zero_end - o_deg, stream);

  const int n2 = 2 * n;
  const int nTiles = (n2 + 1023) / 1024;
  k_count<<<(E + 255) / 256, 256, 0, stream>>>(rowv, colv, E, degAll, n);
  k_dinv<<<(n + 255) / 256, 256, 0, stream>>>(degAll, dinv, n);
  k_scan1<<<nTiles, 256, 0, stream>>>(degAll, n2, n, offAll, ts);
  k_scan2<<<1, 256, 0, stream>>>(ts, nTiles);
  k_scan3<<<(n2 + 255) / 256, 256, 0, stream>>>(offAll, ts, n2, n, E);
  k_scatter<<<(E + 255) / 256, 256, 0, stream>>>(rowv, colv, E, offAll, curAll, dinv, bat,
                                                 srcIdx, enorm, gS, wS, n);

  // layer 1 scalar aggregation, then fused (rank-1 h1 + relu + layer-2 aggregation)
  k_layer1<<<(n + 255) / 256, 256, 0, stream>>>(x, offAll, srcIdx, enorm, dinv, s, n);
  k_l2in<<<(n + 3) / 4, 256, 0, stream>>>(s, offAll, srcIdx, enorm, dinv, W1, b1,
                                          (float2*)bufB, n);

  // layer 2 GEMM (+bias+relu)
  k_gemm<true><<<dim3(512, 2), 256, 0, stream>>>(bufB, W2, b2, bufA, n);

  // layer 3: stream h2, scatter-accumulate into pooled (agg+pool fused)
  k_agg3pool<<<512, 256, 0, stream>>>((const float2*)bufA, offAll + n + 1, gS, wS, dinv, bat,
                                      pooled, n);
  k_gcount<<<1, 64, 0, stream>>>(bat, gcount, n);
  k_mid<<<NGRAPH, HDIM, 0, stream>>>(pooled, gcount, W3, b3, t1);
  k_out<<<1, 512, 0, stream>>>(t1, Wl, bl, out);
}

// Round 3
// 853.500 us; speedup vs baseline: 1.0022x; 1.0022x over previous
//
#include <hip/hip_runtime.h>

#define HDIM 128
#define NGRAPH 64
#define NCLASS 7

// ---------------- setup: degrees (by dst and by src), dinv ----------------

__global__ void k_count(const int* __restrict__ row, const int* __restrict__ col, int E,
                        int* __restrict__ degAll, int n) {
  int e = blockIdx.x * blockDim.x + threadIdx.x;
  if (e < E) {
    atomicAdd(&degAll[col[e]], 1);      // in-degree (aggregation dst)
    atomicAdd(&degAll[n + row[e]], 1);  // out-degree (src)
  }
}

__global__ void k_dinv(const int* __restrict__ degAll, float* __restrict__ dinv, int n) {
  int i = blockIdx.x * blockDim.x + threadIdx.x;
  if (i < n) dinv[i] = rsqrtf((float)(degAll[i] + 1));  // +1 self-loop
}

// exclusive scan of degAll[0..2n) -> offAll, writing with +1 index shift for i>=n
// offAll layout: [0..n] = col-CSR offsets, [n+1..2n+1] = row-CSR offsets
__global__ void k_scan1(const int* __restrict__ in, int n2, int n, int* __restrict__ outAll,
                        int* __restrict__ tileSums) {
  __shared__ int sh[256];
  int t = threadIdx.x;
  int base = blockIdx.x * 1024 + t * 4;
  int v[4], sum = 0;
#pragma unroll
  for (int j = 0; j < 4; j++) {
    int idx = base + j;
    int x = (idx < n2) ? in[idx] : 0;
    v[j] = sum; sum += x;
  }
  sh[t] = sum; __syncthreads();
  for (int o = 1; o < 256; o <<= 1) {
    int val = (t >= o) ? sh[t - o] : 0;
    __syncthreads();
    sh[t] += val;
    __syncthreads();
  }
  int excl = (t == 0) ? 0 : sh[t - 1];
  if (t == 255) tileSums[blockIdx.x] = sh[255];
#pragma unroll
  for (int j = 0; j < 4; j++) {
    int idx = base + j;
    if (idx < n2) outAll[idx + (idx >= n ? 1 : 0)] = excl + v[j];
  }
}

__global__ void k_scan2(int* __restrict__ tileSums, int numTiles) {
  __shared__ int sh[256];
  int t = threadIdx.x;
  sh[t] = (t < numTiles) ? tileSums[t] : 0;
  __syncthreads();
  for (int o = 1; o < 256; o <<= 1) {
    int val = (t >= o) ? sh[t - o] : 0;
    __syncthreads();
    sh[t] += val;
    __syncthreads();
  }
  if (t < numTiles) tileSums[t] = (t == 0) ? 0 : sh[t - 1];
}

__global__ void k_scan3(int* __restrict__ offAll, const int* __restrict__ tileSums,
                        int n2, int n, int E) {
  int i = blockIdx.x * blockDim.x + threadIdx.x;
  if (i < n2) {
    int pos = i + (i >= n ? 1 : 0);
    int adj = tileSums[i >> 10] - (i >= n ? E : 0);
    offAll[pos] += adj;
  }
  if (i == 0) { offAll[n] = E; offAll[n2 + 1] = E; }
}

// build both CSRs in one pass; row-CSR payload packed as (graph, weight-bits)
__global__ void k_scatter(const int* __restrict__ row, const int* __restrict__ col, int E,
                          const int* __restrict__ offAll, int* __restrict__ curAll,
                          const float* __restrict__ dinv, const int* __restrict__ batch,
                          int* __restrict__ srcIdx, float* __restrict__ enorm,
                          int2* __restrict__ gw, int n) {
  int e = blockIdx.x * blockDim.x + threadIdx.x;
  if (e >= E) return;
  int r = row[e], c = col[e];
  float w = dinv[r] * dinv[c];
  int pC = offAll[c] + atomicAdd(&curAll[c], 1);
  srcIdx[pC] = r;
  enorm[pC] = w;
  int pR = offAll[n + 1 + r] + atomicAdd(&curAll[n + r], 1);
  gw[pR] = make_int2(batch[c], __float_as_int(w));
}

// ---------------- layer 1: s = A_norm . x (scalar aggregation) ----------------

__global__ void k_layer1(const float* __restrict__ x, const int* __restrict__ off,
                         const int* __restrict__ srcIdx, const float* __restrict__ enorm,
                         const float* __restrict__ dinv, float* __restrict__ s, int n) {
  int i = blockIdx.x * blockDim.x + threadIdx.x;
  if (i >= n) return;
  float di = dinv[i];
  float acc = di * di * x[i];
  int e0 = off[i], e1 = off[i + 1];
  for (int e = e0; e < e1; e++) acc = fmaf(enorm[e], x[srcIdx[e]], acc);
  s[i] = acc;
}

// ---------------- fused: h1 = relu(s*W1+b1) recomputed per edge + agg2 ----------------
// z[i][j] = nself*relu(s[i]W1[j]+b1[j]) + sum_e w_e * relu(s[src]W1[j]+b1[j])

__global__ void __launch_bounds__(256) k_l2in(const float* __restrict__ s,
                                              const int* __restrict__ off,
                                              const int* __restrict__ srcIdx,
                                              const float* __restrict__ enorm,
                                              const float* __restrict__ dinv,
                                              const float* __restrict__ W1,
                                              const float* __restrict__ b1,
                                              float2* __restrict__ z, int n) {
  int node = blockIdx.x * 4 + (threadIdx.x >> 6);
  if (node >= n) return;
  int l = threadIdx.x & 63;
  float2 w1 = ((const float2*)W1)[l];
  float2 bv = ((const float2*)b1)[l];
  float di = dinv[node];
  float nself = di * di;
  float sv = s[node];
  float2 acc;
  acc.x = nself * fmaxf(fmaf(sv, w1.x, bv.x), 0.f);
  acc.y = nself * fmaxf(fmaf(sv, w1.y, bv.y), 0.f);
  int e0 = off[node], e1 = off[node + 1];
  for (int e = e0; e < e1; e++) {
    float ss = s[srcIdx[e]];
    float w = enorm[e];
    acc.x = fmaf(w, fmaxf(fmaf(ss, w1.x, bv.x), 0.f), acc.x);
    acc.y = fmaf(w, fmaxf(fmaf(ss, w1.y, bv.y), 0.f), acc.y);
  }
  z[(size_t)node * 64 + l] = acc;
}

// ---------------- GEMM: (n x 128) @ (128 x 128) + bias + relu ----------------
// 64r x 64c tile, 256 threads, 4x4 register tile, k-vectorized b128 reads.

template <bool RELU>
__global__ void __launch_bounds__(256, 2)
k_gemm(const float* __restrict__ A, const float* __restrict__ W,
       const float* __restrict__ bias, float* __restrict__ out, int n) {
  __shared__ float4 As4[64 * 32];
  __shared__ float4 Wt4[64 * 32];
  float* Wt = (float*)Wt4;
  const int t = threadIdx.x;
  const int colBase = blockIdx.y << 6;

  // stage Wt (transposed + swizzled) once per block
  for (int l = t; l < 2048; l += 256) {
    int k = l >> 4, c4 = (l & 15) << 2;
    float4 wv = *(const float4*)&W[k * 128 + colBase + c4];
    int kq = k >> 2, kl = k & 3;
    int u = (c4 >> 2) & 7;
    int slot = ((kq ^ u) << 2) | kl;
    Wt[(c4 + 0) * 128 + slot] = wv.x;
    Wt[(c4 + 1) * 128 + slot] = wv.y;
    Wt[(c4 + 2) * 128 + slot] = wv.z;
    Wt[(c4 + 3) * 128 + slot] = wv.w;
  }

  const int cg = (t & 15) << 2;   // 4 cols
  const int rg = (t >> 4) << 2;   // 4 rows
  const int ra = (rg >> 2) & 7;
  const int ca = (cg >> 2) & 7;
  const float4 bv = *(const float4*)&bias[colBase + cg];
  const int numTiles = (n + 63) >> 6;

  for (int tile = blockIdx.x; tile < numTiles; tile += gridDim.x) {
    const int rowBase = tile << 6;
    __syncthreads();  // protects As reuse (and covers Wt staging on first iter)
    for (int l = t; l < 2048; l += 256) {
      int r = l >> 5, kq = l & 31;
      int row = rowBase + r;
      float4 a = (row < n) ? *(const float4*)&A[(size_t)row * 128 + (kq << 2)]
                           : make_float4(0.f, 0.f, 0.f, 0.f);
      As4[r * 32 + (kq ^ ((r >> 2) & 7))] = a;
    }
    __syncthreads();

    float acc[4][4] = {};
    const float4* a0p = &As4[(rg + 0) * 32];
    const float4* a1p = &As4[(rg + 1) * 32];
    const float4* a2p = &As4[(rg + 2) * 32];
    const float4* a3p = &As4[(rg + 3) * 32];
    const float4* w0p = &Wt4[(cg + 0) * 32];
    const float4* w1p = &Wt4[(cg + 1) * 32];
    const float4* w2p = &Wt4[(cg + 2) * 32];
    const float4* w3p = &Wt4[(cg + 3) * 32];
#pragma unroll 8
    for (int kq = 0; kq < 32; kq++) {
      int ia = kq ^ ra, iw = kq ^ ca;
      float4 a[4] = { a0p[ia], a1p[ia], a2p[ia], a3p[ia] };
      float4 w[4] = { w0p[iw], w1p[iw], w2p[iw], w3p[iw] };
#pragma unroll
      for (int i = 0; i < 4; i++)
#pragma unroll
        for (int j = 0; j < 4; j++) {
          float v = acc[i][j];
          v = fmaf(a[i].x, w[j].x, v);
          v = fmaf(a[i].y, w[j].y, v);
          v = fmaf(a[i].z, w[j].z, v);
          v = fmaf(a[i].w, w[j].w, v);
          acc[i][j] = v;
        }
    }

#pragma unroll
    for (int i = 0; i < 4; i++) {
      int row = rowBase + rg + i;
      if (row < n) {
        float4 o4;
        o4.x = acc[i][0] + bv.x;
        o4.y = acc[i][1] + bv.y;
        o4.z = acc[i][2] + bv.z;
        o4.w = acc[i][3] + bv.w;
        if (RELU) {
          o4.x = fmaxf(o4.x, 0.f); o4.y = fmaxf(o4.y, 0.f);
          o4.z = fmaxf(o4.z, 0.f); o4.w = fmaxf(o4.w, 0.f);
        }
        *(float4*)&out[(size_t)row * 128 + colBase + cg] = o4;
      }
    }
  }
}

// ---------------- fused layer-3 aggregation + pooling ----------------
// pooled[g][:] += h2[src][:] * coef for self-loop and every out-edge of src.
// Streams h2 once (coalesced); NATIVE LDS fp32 atomics (unsafeAtomicAdd -> ds_add_f32);
// lane owns features {lane, 64+lane} -> stride-1 LDS (2-way aliasing = free).

__global__ void __launch_bounds__(256) k_agg3pool(const float* __restrict__ h2,
                                                  const int* __restrict__ offR,
                                                  const int2* __restrict__ gw,
                                                  const float* __restrict__ dinv,
                                                  const int* __restrict__ batch,
                                                  float* __restrict__ pooled, int n) {
  __shared__ float lp[NGRAPH * HDIM];
  for (int i = threadIdx.x; i < NGRAPH * HDIM; i += 256) lp[i] = 0.f;
  __syncthreads();
  int lane = threadIdx.x & 63;
  int wv = threadIdx.x >> 6;
  int per = (n + gridDim.x - 1) / gridDim.x;
  int s0 = blockIdx.x * per;
  int s1 = min(s0 + per, n);
  for (int src = s0 + wv; src < s1; src += 4) {
    float hx = h2[(size_t)src * HDIM + lane];
    float hy = h2[(size_t)src * HDIM + 64 + lane];
    float di = dinv[src];
    int g = batch[src];
    float w = di * di;  // self-loop coef
    unsafeAtomicAdd(&lp[g * HDIM + lane], w * hx);
    unsafeAtomicAdd(&lp[g * HDIM + 64 + lane], w * hy);
    int e0 = offR[src], e1 = offR[src + 1];
    for (int e = e0; e < e1; e++) {
      int2 p = gw[e];
      float we = __int_as_float(p.y);
      unsafeAtomicAdd(&lp[p.x * HDIM + lane], we * hx);
      unsafeAtomicAdd(&lp[p.x * HDIM + 64 + lane], we * hy);
    }
  }
  __syncthreads();
  for (int i = threadIdx.x; i < NGRAPH * HDIM; i += 256) {
    float v = lp[i];
    if (v != 0.f) unsafeAtomicAdd(&pooled[i], v);
  }
}

// graph sizes via binary search on sorted batch (one wave)
__global__ void k_gcount(const int* __restrict__ batch, float* __restrict__ gcount, int n) {
  int g = threadIdx.x;
  if (g >= NGRAPH) return;
  int lo = 0, hi = n;
  while (lo < hi) { int m = (lo + hi) >> 1; if (batch[m] < g) lo = m + 1; else hi = m; }
  int a = lo;
  lo = 0; hi = n;
  while (lo < hi) { int m = (lo + hi) >> 1; if (batch[m] < g + 1) lo = m + 1; else hi = m; }
  gcount[g] = (float)(lo - a);
}

// t1[g][j] = (pooledSum[g] . W3[:,j]) / cnt[g] + b3[j]
__global__ void k_mid(const float* __restrict__ pooled, const float* __restrict__ gcount,
                      const float* __restrict__ W3, const float* __restrict__ b3,
                      float* __restrict__ t1) {
  int g = blockIdx.x, j = threadIdx.x;
  float inv = 1.f / fmaxf(gcount[g], 1.f);
  float acc = 0.f;
  for (int k = 0; k < HDIM; k++) acc = fmaf(pooled[g * HDIM + k], W3[k * HDIM + j], acc);
  t1[g * HDIM + j] = acc * inv + b3[j];
}

__global__ void k_out(const float* __restrict__ t1, const float* __restrict__ Wl,
                      const float* __restrict__ bl, float* __restrict__ out) {
  int t = threadIdx.x;
  int g = t >> 3, c = t & 7;
  if (g >= NGRAPH || c >= NCLASS) return;
  float acc = 0.f;
  for (int k = 0; k < HDIM; k++) acc = fmaf(t1[g * HDIM + k], Wl[k * NCLASS + c], acc);
  out[g * NCLASS + c] = acc + bl[c];
}

// ---------------- host ----------------

extern "C" void kernel_launch(void* const* d_in, const int* in_sizes, int n_in,
                              void* d_out, int out_size, void* d_ws, size_t ws_size,
                              hipStream_t stream) {
  const float* x   = (const float*)d_in[0];
  const int*   ei  = (const int*)d_in[1];
  const int*   bat = (const int*)d_in[2];
  const float* W1  = (const float*)d_in[3];
  const float* b1  = (const float*)d_in[4];
  const float* W2  = (const float*)d_in[5];
  const float* b2  = (const float*)d_in[6];
  const float* W3  = (const float*)d_in[7];
  const float* b3  = (const float*)d_in[8];
  const float* Wl  = (const float*)d_in[9];
  const float* bl  = (const float*)d_in[10];
  float* out = (float*)d_out;

  const int n = in_sizes[0];       // N (F_IN == 1)
  const int E = in_sizes[1] / 2;
  const int* rowv = ei;            // edge_index[0] : message source
  const int* colv = ei + E;        // edge_index[1] : aggregation destination

  char* w = (char*)d_ws;
  size_t o = 0;
  auto alloc = [&](size_t bytes) {
    size_t r = (o + 255) & ~(size_t)255;
    o = r + bytes;
    return r;
  };
  // zero-init region (contiguous): degAll(2n), curAll(2n), pooled
  size_t o_deg  = alloc((size_t)2 * n * 4);
  size_t o_cur  = alloc((size_t)2 * n * 4);
  size_t o_pool = alloc((size_t)NGRAPH * HDIM * 4);
  size_t zero_end = o;
  size_t o_off  = alloc(((size_t)2 * n + 2) * 4);
  size_t o_ts   = alloc(256 * 4);
  size_t o_dinv = alloc((size_t)n * 4);
  size_t o_s    = alloc((size_t)n * 4);
  size_t o_gcnt = alloc((size_t)NGRAPH * 4);
  size_t o_t1   = alloc((size_t)NGRAPH * HDIM * 4);
  size_t o_src  = alloc((size_t)E * 4);
  size_t o_nrm  = alloc((size_t)E * 4);
  size_t o_gw   = alloc((size_t)E * 8);
  size_t o_bufA = alloc((size_t)n * HDIM * 4);
  size_t o_bufB = alloc((size_t)n * HDIM * 4);
  (void)ws_size; (void)n_in; (void)out_size;

  int*   degAll = (int*)(w + o_deg);
  int*   curAll = (int*)(w + o_cur);
  float* pooled = (float*)(w + o_pool);
  int*   offAll = (int*)(w + o_off);
  int*   ts     = (int*)(w + o_ts);
  float* dinv   = (float*)(w + o_dinv);
  float* s      = (float*)(w + o_s);
  float* gcount = (float*)(w + o_gcnt);
  float* t1     = (float*)(w + o_t1);
  int*   srcIdx = (int*)(w + o_src);
  float* enorm  = (float*)(w + o_nrm);
  int2*  gw     = (int2*)(w + o_gw);
  float* bufA   = (float*)(w + o_bufA);  // h2 (gemm out)
  float* bufB   = (float*)(w + o_bufB);  // gemm in (fused agg2 out)

  hipMemsetAsync(w + o_deg, 0, zero_end - o_deg, stream);

  const int n2 = 2 * n;
  const int nTiles = (n2 + 1023) / 1024;
  k_count<<<(E + 255) / 256, 256, 0, stream>>>(rowv, colv, E, degAll, n);
  k_dinv<<<(n + 255) / 256, 256, 0, stream>>>(degAll, dinv, n);
  k_scan1<<<nTiles, 256, 0, stream>>>(degAll, n2, n, offAll, ts);
  k_scan2<<<1, 256, 0, stream>>>(ts, nTiles);
  k_scan3<<<(n2 + 255) / 256, 256, 0, stream>>>(offAll, ts, n2, n, E);
  k_scatter<<<(E + 255) / 256, 256, 0, stream>>>(rowv, colv, E, offAll, curAll, dinv, bat,
                                                 srcIdx, enorm, gw, n);

  // layer 1 scalar aggregation, then fused (rank-1 h1 + relu + layer-2 aggregation)
  k_layer1<<<(n + 255) / 256, 256, 0, stream>>>(x, offAll, srcIdx, enorm, dinv, s, n);
  k_l2in<<<(n + 3) / 4, 256, 0, stream>>>(s, offAll, srcIdx, enorm, dinv, W1, b1,
                                          (float2*)bufB, n);

  // layer 2 GEMM (+bias+relu)
  k_gemm<true><<<dim3(512, 2), 256, 0, stream>>>(bufB, W2, b2, bufA, n);

  // layer 3: stream h2, scatter-accumulate into pooled (agg+pool fused)
  k_agg3pool<<<512, 256, 0, stream>>>(bufA, offAll + n + 1, gw, dinv, bat, pooled, n);
  k_gcount<<<1, 64, 0, stream>>>(bat, gcount, n);
  k_mid<<<NGRAPH, HDIM, 0, stream>>>(pooled, gcount, W3, b3, t1);
  k_out<<<1, 512, 0, stream>>>(t1, Wl, bl, out);
}

// Round 4
// 375.476 us; speedup vs baseline: 2.2782x; 2.2731x over previous
//
#include <hip/hip_runtime.h>

#define HDIM 128
#define NGRAPH 64
#define NCLASS 7
#define PG_NODES 192  // nodes per k_pgemm block (3 sub-chunks of 64)

// ---------------- setup: in-degree, dinv, dst-CSR ----------------

__global__ void k_count(const int* __restrict__ col, int E, int* __restrict__ deg) {
  int e = blockIdx.x * blockDim.x + threadIdx.x;
  if (e < E) atomicAdd(&deg[col[e]], 1);
}

__global__ void k_dinv(const int* __restrict__ deg, float* __restrict__ dinv, int n) {
  int i = blockIdx.x * blockDim.x + threadIdx.x;
  if (i < n) dinv[i] = rsqrtf((float)(deg[i] + 1));  // +1 self-loop
}

__global__ void k_scan1(const int* __restrict__ in, int n, int* __restrict__ outLocal,
                        int* __restrict__ tileSums) {
  __shared__ int sh[256];
  int t = threadIdx.x;
  int base = blockIdx.x * 1024 + t * 4;
  int v[4], sum = 0;
#pragma unroll
  for (int j = 0; j < 4; j++) {
    int idx = base + j;
    int x = (idx < n) ? in[idx] : 0;
    v[j] = sum; sum += x;
  }
  sh[t] = sum; __syncthreads();
  for (int o = 1; o < 256; o <<= 1) {
    int val = (t >= o) ? sh[t - o] : 0;
    __syncthreads();
    sh[t] += val;
    __syncthreads();
  }
  int excl = (t == 0) ? 0 : sh[t - 1];
  if (t == 255) tileSums[blockIdx.x] = sh[255];
#pragma unroll
  for (int j = 0; j < 4; j++) {
    int idx = base + j;
    if (idx < n) outLocal[idx] = excl + v[j];
  }
}

__global__ void k_scan2(int* __restrict__ tileSums, int numTiles) {
  __shared__ int sh[128];
  int t = threadIdx.x;
  sh[t] = (t < numTiles) ? tileSums[t] : 0;
  __syncthreads();
  for (int o = 1; o < 128; o <<= 1) {
    int val = (t >= o) ? sh[t - o] : 0;
    __syncthreads();
    sh[t] += val;
    __syncthreads();
  }
  if (t < numTiles) tileSums[t] = (t == 0) ? 0 : sh[t - 1];
}

__global__ void k_scan3(int* __restrict__ off, const int* __restrict__ tileSums, int n, int E) {
  int i = blockIdx.x * blockDim.x + threadIdx.x;
  if (i < n) off[i] += tileSums[i >> 10];
  if (i == 0) off[n] = E;
}

__global__ void k_scatter(const int* __restrict__ row, const int* __restrict__ col, int E,
                          const int* __restrict__ off, int* __restrict__ cursor,
                          const float* __restrict__ dinv,
                          int* __restrict__ srcIdx, float* __restrict__ enorm) {
  int e = blockIdx.x * blockDim.x + threadIdx.x;
  if (e >= E) return;
  int r = row[e], c = col[e];
  int pos = off[c] + atomicAdd(&cursor[c], 1);
  srcIdx[pos] = r;
  enorm[pos] = dinv[r] * dinv[c];
}

// ---------------- layer 1: s = A_norm . x (scalar aggregation, unroll-4) ----------------

__global__ void k_layer1(const float* __restrict__ x, const int* __restrict__ off,
                         const int* __restrict__ srcIdx, const float* __restrict__ enorm,
                         const float* __restrict__ dinv, float* __restrict__ s, int n) {
  int i = blockIdx.x * blockDim.x + threadIdx.x;
  if (i >= n) return;
  float di = dinv[i];
  float acc = di * di * x[i];
  int e0 = off[i], e1 = off[i + 1];
  int e = e0;
  for (; e + 4 <= e1; e += 4) {
    int i0 = srcIdx[e], i1 = srcIdx[e + 1], i2 = srcIdx[e + 2], i3 = srcIdx[e + 3];
    float w0 = enorm[e], w1 = enorm[e + 1], w2 = enorm[e + 2], w3 = enorm[e + 3];
    float x0 = x[i0], x1 = x[i1], x2 = x[i2], x3 = x[i3];
    acc = fmaf(w0, x0, acc);
    acc = fmaf(w1, x1, acc);
    acc = fmaf(w2, x2, acc);
    acc = fmaf(w3, x3, acc);
  }
  for (; e < e1; e++) acc = fmaf(enorm[e], x[srcIdx[e]], acc);
  s[i] = acc;
}

// ---------------- fused: h1 = relu(s*W1+b1) recomputed per edge + agg2 ----------------

__global__ void __launch_bounds__(256) k_l2in(const float* __restrict__ s,
                                              const int* __restrict__ off,
                                              const int* __restrict__ srcIdx,
                                              const float* __restrict__ enorm,
                                              const float* __restrict__ dinv,
                                              const float* __restrict__ W1,
                                              const float* __restrict__ b1,
                                              float2* __restrict__ z, int n) {
  int node = blockIdx.x * 4 + (threadIdx.x >> 6);
  if (node >= n) return;
  int l = threadIdx.x & 63;
  float2 w1 = ((const float2*)W1)[l];
  float2 bv = ((const float2*)b1)[l];
  float di = dinv[node];
  float nself = di * di;
  float sv = s[node];
  float2 acc;
  acc.x = nself * fmaxf(fmaf(sv, w1.x, bv.x), 0.f);
  acc.y = nself * fmaxf(fmaf(sv, w1.y, bv.y), 0.f);
  int e0 = off[node], e1 = off[node + 1];
  int e = e0;
  for (; e + 4 <= e1; e += 4) {
    int i0 = srcIdx[e], i1 = srcIdx[e + 1], i2 = srcIdx[e + 2], i3 = srcIdx[e + 3];
    float u0 = enorm[e], u1 = enorm[e + 1], u2 = enorm[e + 2], u3 = enorm[e + 3];
    float s0 = s[i0], s1 = s[i1], s2 = s[i2], s3 = s[i3];
    acc.x = fmaf(u0, fmaxf(fmaf(s0, w1.x, bv.x), 0.f), acc.x);
    acc.y = fmaf(u0, fmaxf(fmaf(s0, w1.y, bv.y), 0.f), acc.y);
    acc.x = fmaf(u1, fmaxf(fmaf(s1, w1.x, bv.x), 0.f), acc.x);
    acc.y = fmaf(u1, fmaxf(fmaf(s1, w1.y, bv.y), 0.f), acc.y);
    acc.x = fmaf(u2, fmaxf(fmaf(s2, w1.x, bv.x), 0.f), acc.x);
    acc.y = fmaf(u2, fmaxf(fmaf(s2, w1.y, bv.y), 0.f), acc.y);
    acc.x = fmaf(u3, fmaxf(fmaf(s3, w1.x, bv.x), 0.f), acc.x);
    acc.y = fmaf(u3, fmaxf(fmaf(s3, w1.y, bv.y), 0.f), acc.y);
  }
  for (; e < e1; e++) {
    float ss = s[srcIdx[e]];
    float w = enorm[e];
    acc.x = fmaf(w, fmaxf(fmaf(ss, w1.x, bv.x), 0.f), acc.x);
    acc.y = fmaf(w, fmaxf(fmaf(ss, w1.y, bv.y), 0.f), acc.y);
  }
  z[(size_t)node * 64 + l] = acc;
}

// ---------------- GEMM: (n x 128) @ (128 x 128) + bias + relu ----------------

template <bool RELU>
__global__ void __launch_bounds__(256, 2)
k_gemm(const float* __restrict__ A, const float* __restrict__ W,
       const float* __restrict__ bias, float* __restrict__ out, int n) {
  __shared__ float4 As4[64 * 32];
  __shared__ float4 Wt4[64 * 32];
  float* Wt = (float*)Wt4;
  const int t = threadIdx.x;
  const int colBase = blockIdx.y << 6;

  for (int l = t; l < 2048; l += 256) {
    int k = l >> 4, c4 = (l & 15) << 2;
    float4 wv = *(const float4*)&W[k * 128 + colBase + c4];
    int kq = k >> 2, kl = k & 3;
    int u = (c4 >> 2) & 7;
    int slot = ((kq ^ u) << 2) | kl;
    Wt[(c4 + 0) * 128 + slot] = wv.x;
    Wt[(c4 + 1) * 128 + slot] = wv.y;
    Wt[(c4 + 2) * 128 + slot] = wv.z;
    Wt[(c4 + 3) * 128 + slot] = wv.w;
  }

  const int cg = (t & 15) << 2;
  const int rg = (t >> 4) << 2;
  const int ra = (rg >> 2) & 7;
  const int ca = (cg >> 2) & 7;
  const float4 bv = *(const float4*)&bias[colBase + cg];
  const int numTiles = (n + 63) >> 6;

  for (int tile = blockIdx.x; tile < numTiles; tile += gridDim.x) {
    const int rowBase = tile << 6;
    __syncthreads();
    for (int l = t; l < 2048; l += 256) {
      int r = l >> 5, kq = l & 31;
      int row = rowBase + r;
      float4 a = (row < n) ? *(const float4*)&A[(size_t)row * 128 + (kq << 2)]
                           : make_float4(0.f, 0.f, 0.f, 0.f);
      As4[r * 32 + (kq ^ ((r >> 2) & 7))] = a;
    }
    __syncthreads();

    float acc[4][4] = {};
    const float4* a0p = &As4[(rg + 0) * 32];
    const float4* a1p = &As4[(rg + 1) * 32];
    const float4* a2p = &As4[(rg + 2) * 32];
    const float4* a3p = &As4[(rg + 3) * 32];
    const float4* w0p = &Wt4[(cg + 0) * 32];
    const float4* w1p = &Wt4[(cg + 1) * 32];
    const float4* w2p = &Wt4[(cg + 2) * 32];
    const float4* w3p = &Wt4[(cg + 3) * 32];
#pragma unroll 8
    for (int kq = 0; kq < 32; kq++) {
      int ia = kq ^ ra, iw = kq ^ ca;
      float4 a[4] = { a0p[ia], a1p[ia], a2p[ia], a3p[ia] };
      float4 w[4] = { w0p[iw], w1p[iw], w2p[iw], w3p[iw] };
#pragma unroll
      for (int i = 0; i < 4; i++)
#pragma unroll
        for (int j = 0; j < 4; j++) {
          float v = acc[i][j];
          v = fmaf(a[i].x, w[j].x, v);
          v = fmaf(a[i].y, w[j].y, v);
          v = fmaf(a[i].z, w[j].z, v);
          v = fmaf(a[i].w, w[j].w, v);
          acc[i][j] = v;
        }
    }

#pragma unroll
    for (int i = 0; i < 4; i++) {
      int row = rowBase + rg + i;
      if (row < n) {
        float4 o4;
        o4.x = acc[i][0] + bv.x;
        o4.y = acc[i][1] + bv.y;
        o4.z = acc[i][2] + bv.z;
        o4.w = acc[i][3] + bv.w;
        if (RELU) {
          o4.x = fmaxf(o4.x, 0.f); o4.y = fmaxf(o4.y, 0.f);
          o4.z = fmaxf(o4.z, 0.f); o4.w = fmaxf(o4.w, 0.f);
        }
        *(float4*)&out[(size_t)row * 128 + colBase + cg] = o4;
      }
    }
  }
}

// ---------------- layer 3 + pool as dense P^T * H ----------------
// P[src][g] = sum over out-edges of src into graph g of w, plus self coef.

__global__ void k_pbuild(const int* __restrict__ row, const int* __restrict__ col, int E,
                         const float* __restrict__ dinv, const int* __restrict__ batch,
                         float* __restrict__ P, int n) {
  int e = blockIdx.x * blockDim.x + threadIdx.x;
  if (e < E) {
    int r = row[e], c = col[e];
    unsafeAtomicAdd(&P[(size_t)r * NGRAPH + batch[c]], dinv[r] * dinv[c]);
  } else if (e - E < n) {
    int i = e - E;
    float d = dinv[i];
    unsafeAtomicAdd(&P[(size_t)i * NGRAPH + batch[i]], d * d);
  }
}

// partials[b][g][j] = sum over block b's nodes of P[i][g] * H[i][j]
// 256 thr; thread owns 8 g x 4 j. Per i: 1 b128 (H) + 2 b128 (P) + 32 fma.
__global__ void __launch_bounds__(256) k_pgemm(const float* __restrict__ H,
                                               const float* __restrict__ P,
                                               float* __restrict__ partials, int n) {
  __shared__ float4 Hl4[64 * 32];  // [i][j-quad]
  __shared__ float4 Pl4[64 * 16];  // [i][g-quad]
  const int t = threadIdx.x;
  const int jl = t & 31;           // j-quad
  const int gq = (t >> 5) << 1;    // g-octet = 2 consecutive float4 slots
  float4 acc[8];
#pragma unroll
  for (int i = 0; i < 8; i++) acc[i] = make_float4(0.f, 0.f, 0.f, 0.f);
  const int base0 = blockIdx.x * PG_NODES;

  for (int sub = 0; sub < PG_NODES / 64; sub++) {
    const int base = base0 + sub * 64;
    __syncthreads();
    for (int l = t; l < 2048; l += 256) {
      int i = l >> 5, q = l & 31;
      int node = base + i;
      Hl4[l] = (node < n) ? *(const float4*)&H[(size_t)node * 128 + (q << 2)]
                          : make_float4(0.f, 0.f, 0.f, 0.f);
    }
    for (int l = t; l < 1024; l += 256) {
      int i = l >> 4, q = l & 15;
      int node = base + i;
      Pl4[l] = (node < n) ? *(const float4*)&P[(size_t)node * NGRAPH + (q << 2)]
                          : make_float4(0.f, 0.f, 0.f, 0.f);
    }
    __syncthreads();

#define FMA4(A, PV) \
  A.x = fmaf(PV, hv.x, A.x); A.y = fmaf(PV, hv.y, A.y); \
  A.z = fmaf(PV, hv.z, A.z); A.w = fmaf(PV, hv.w, A.w);
#pragma unroll 4
    for (int i = 0; i < 64; i++) {
      float4 hv = Hl4[i * 32 + jl];
      float4 pa = Pl4[i * 16 + gq];
      float4 pb = Pl4[i * 16 + gq + 1];
      FMA4(acc[0], pa.x) FMA4(acc[1], pa.y) FMA4(acc[2], pa.z) FMA4(acc[3], pa.w)
      FMA4(acc[4], pb.x) FMA4(acc[5], pb.y) FMA4(acc[6], pb.z) FMA4(acc[7], pb.w)
    }
#undef FMA4
  }

  float* dst = &partials[(size_t)blockIdx.x * (NGRAPH * HDIM)];
  int gb = (t >> 5) << 3;
#pragma unroll
  for (int gi = 0; gi < 8; gi++)
    *(float4*)&dst[(gb + gi) * HDIM + (jl << 2)] = acc[gi];
}

// 2-level reduce of partials into pooled. grid (32, 8), block 256.
__global__ void k_reduce(const float* __restrict__ partials, float* __restrict__ pooled,
                         int nparts) {
  int cell = blockIdx.x * 256 + threadIdx.x;
  int stride = gridDim.y;
  int p = blockIdx.y;
  float a0 = 0.f, a1 = 0.f, a2 = 0.f, a3 = 0.f;
  for (; p + 3 * stride < nparts; p += 4 * stride) {
    a0 += partials[(size_t)p * 8192 + cell];
    a1 += partials[(size_t)(p + stride) * 8192 + cell];
    a2 += partials[(size_t)(p + 2 * stride) * 8192 + cell];
    a3 += partials[(size_t)(p + 3 * stride) * 8192 + cell];
  }
  for (; p < nparts; p += stride) a0 += partials[(size_t)p * 8192 + cell];
  unsafeAtomicAdd(&pooled[cell], (a0 + a1) + (a2 + a3));
}

// graph sizes via binary search on sorted batch (one wave)
__global__ void k_gcount(const int* __restrict__ batch, float* __restrict__ gcount, int n) {
  int g = threadIdx.x;
  if (g >= NGRAPH) return;
  int lo = 0, hi = n;
  while (lo < hi) { int m = (lo + hi) >> 1; if (batch[m] < g) lo = m + 1; else hi = m; }
  int a = lo;
  lo = 0; hi = n;
  while (lo < hi) { int m = (lo + hi) >> 1; if (batch[m] < g + 1) lo = m + 1; else hi = m; }
  gcount[g] = (float)(lo - a);
}

__global__ void k_mid(const float* __restrict__ pooled, const float* __restrict__ gcount,
                      const float* __restrict__ W3, const float* __restrict__ b3,
                      float* __restrict__ t1) {
  int g = blockIdx.x, j = threadIdx.x;
  float inv = 1.f / fmaxf(gcount[g], 1.f);
  float acc = 0.f;
  for (int k = 0; k < HDIM; k++) acc = fmaf(pooled[g * HDIM + k], W3[k * HDIM + j], acc);
  t1[g * HDIM + j] = acc * inv + b3[j];
}

__global__ void k_out(const float* __restrict__ t1, const float* __restrict__ Wl,
                      const float* __restrict__ bl, float* __restrict__ out) {
  int t = threadIdx.x;
  int g = t >> 3, c = t & 7;
  if (g >= NGRAPH || c >= NCLASS) return;
  float acc = 0.f;
  for (int k = 0; k < HDIM; k++) acc = fmaf(t1[g * HDIM + k], Wl[k * NCLASS + c], acc);
  out[g * NCLASS + c] = acc + bl[c];
}

// ---------------- host ----------------

extern "C" void kernel_launch(void* const* d_in, const int* in_sizes, int n_in,
                              void* d_out, int out_size, void* d_ws, size_t ws_size,
                              hipStream_t stream) {
  const float* x   = (const float*)d_in[0];
  const int*   ei  = (const int*)d_in[1];
  const int*   bat = (const int*)d_in[2];
  const float* W1  = (const float*)d_in[3];
  const float* b1  = (const float*)d_in[4];
  const float* W2  = (const float*)d_in[5];
  const float* b2  = (const float*)d_in[6];
  const float* W3  = (const float*)d_in[7];
  const float* b3  = (const float*)d_in[8];
  const float* Wl  = (const float*)d_in[9];
  const float* bl  = (const float*)d_in[10];
  float* out = (float*)d_out;

  const int n = in_sizes[0];
  const int E = in_sizes[1] / 2;
  const int* rowv = ei;            // edge_index[0] : message source
  const int* colv = ei + E;        // edge_index[1] : aggregation destination

  char* w = (char*)d_ws;
  size_t o = 0;
  auto alloc = [&](size_t bytes) {
    size_t r = (o + 255) & ~(size_t)255;
    o = r + bytes;
    return r;
  };
  // zero-init region (contiguous): deg, cursor, pooled
  size_t o_deg  = alloc((size_t)n * 4);
  size_t o_cur  = alloc((size_t)n * 4);
  size_t o_pool = alloc((size_t)NGRAPH * HDIM * 4);
  size_t zero_end = o;
  size_t o_off  = alloc(((size_t)n + 1) * 4);
  size_t o_ts   = alloc(256 * 4);
  size_t o_dinv = alloc((size_t)n * 4);
  size_t o_s    = alloc((size_t)n * 4);
  size_t o_gcnt = alloc((size_t)NGRAPH * 4);
  size_t o_t1   = alloc((size_t)NGRAPH * HDIM * 4);
  size_t o_src  = alloc((size_t)E * 4);
  size_t o_nrm  = alloc((size_t)E * 4);
  size_t o_bufA = alloc((size_t)n * HDIM * 4);
  size_t o_bufB = alloc((size_t)n * HDIM * 4);
  (void)ws_size; (void)n_in; (void)out_size;

  int*   deg    = (int*)(w + o_deg);
  int*   cursor = (int*)(w + o_cur);
  float* pooled = (float*)(w + o_pool);
  int*   off    = (int*)(w + o_off);
  int*   ts     = (int*)(w + o_ts);
  float* dinv   = (float*)(w + o_dinv);
  float* s      = (float*)(w + o_s);
  float* gcount = (float*)(w + o_gcnt);
  float* t1     = (float*)(w + o_t1);
  int*   srcIdx = (int*)(w + o_src);
  float* enorm  = (float*)(w + o_nrm);
  float* bufA   = (float*)(w + o_bufA);  // h2 (gemm out)
  float* bufB   = (float*)(w + o_bufB);  // gemm in; later: P + partials
  float* P        = bufB;                                    // 25.6 MB
  float* partials = (float*)((char*)bufB + (size_t)n * NGRAPH * 4);

  hipMemsetAsync(w + o_deg, 0, zero_end - o_deg, stream);

  const int nTiles = (n + 1023) / 1024;
  k_count<<<(E + 255) / 256, 256, 0, stream>>>(colv, E, deg);
  k_dinv<<<(n + 255) / 256, 256, 0, stream>>>(deg, dinv, n);
  k_scan1<<<nTiles, 256, 0, stream>>>(deg, n, off, ts);
  k_scan2<<<1, 128, 0, stream>>>(ts, nTiles);
  k_scan3<<<(n + 255) / 256, 256, 0, stream>>>(off, ts, n, E);
  k_scatter<<<(E + 255) / 256, 256, 0, stream>>>(rowv, colv, E, off, cursor, dinv,
                                                 srcIdx, enorm);

  // layer 1 scalar aggregation, then fused (rank-1 h1 + relu + layer-2 aggregation)
  k_layer1<<<(n + 255) / 256, 256, 0, stream>>>(x, off, srcIdx, enorm, dinv, s, n);
  k_l2in<<<(n + 3) / 4, 256, 0, stream>>>(s, off, srcIdx, enorm, dinv, W1, b1,
                                          (float2*)bufB, n);

  // layer 2 GEMM (+bias+relu): bufB -> bufA
  k_gemm<true><<<dim3(512, 2), 256, 0, stream>>>(bufB, W2, b2, bufA, n);

  // layer 3 + pool: pooled = P^T * h2 (bufB is dead after gemm; reuse for P/partials)
  hipMemsetAsync(P, 0, (size_t)n * NGRAPH * 4, stream);
  k_pbuild<<<(E + n + 255) / 256, 256, 0, stream>>>(rowv, colv, E, dinv, bat, P, n);
  const int nPB = (n + PG_NODES - 1) / PG_NODES;
  k_pgemm<<<nPB, 256, 0, stream>>>(bufA, P, partials, n);
  k_reduce<<<dim3(32, 8), 256, 0, stream>>>(partials, pooled, nPB);

  k_gcount<<<1, 64, 0, stream>>>(bat, gcount, n);
  k_mid<<<NGRAPH, HDIM, 0, stream>>>(pooled, gcount, W3, b3, t1);
  k_out<<<1, 512, 0, stream>>>(t1, Wl, bl, out);
}